// Round 1
// baseline (2517.156 us; speedup 1.0000x reference)
//
#include <hip/hip_runtime.h>
#include <stdint.h>

#define N_NODES 100000
#define N_EDGES 500000
#define D 128
#define NTILES 6250   // N_NODES / 16

typedef __bf16 bf16x8 __attribute__((ext_vector_type(8)));
typedef float f32x4 __attribute__((ext_vector_type(4)));

__device__ __forceinline__ unsigned short f2bf(float f) {
    union { float f; unsigned u; } v; v.f = f;
    unsigned u = v.u;
    u += 0x7fffu + ((u >> 16) & 1u);   // round-to-nearest-even
    return (unsigned short)(u >> 16);
}

// Shuffle X (f32, row-major) into MFMA A-fragment order, bf16.
// Entry index (bf16x8 units): (t*4 + s)*64 + l  holds X[t*16 + (l&15)][s*32 + (l>>4)*8 + j]
__global__ __launch_bounds__(256) void prep_x_k(const float* __restrict__ X,
                                                unsigned short* __restrict__ fx) {
    const int t = blockIdx.x;          // tile of 16 rows
    const int u = threadIdx.x;         // u = s*64 + l
    const int l = u & 63;
    const int s = u >> 6;
    const int row = t * 16 + (l & 15);
    const int col = s * 32 + ((l >> 4) << 3);
    const float4* src = reinterpret_cast<const float4*>(X + row * D + col);
    const float4 f0 = src[0];
    const float4 f1 = src[1];
    uint4 o;
    o.x = f2bf(f0.x) | ((unsigned)f2bf(f0.y) << 16);
    o.y = f2bf(f0.z) | ((unsigned)f2bf(f0.w) << 16);
    o.z = f2bf(f1.x) | ((unsigned)f2bf(f1.y) << 16);
    o.w = f2bf(f1.z) | ((unsigned)f2bf(f1.w) << 16);
    reinterpret_cast<uint4*>(fx)[t * 256 + u] = o;
}

// Shuffle the 4 weight matrices (W0, W[0..2]) into B-fragment order, bf16.
// Matrix m entry ((n*4 + s)*64 + l) holds Wm[s*32 + (l>>4)*8 + j][n*16 + (l&15)]
__global__ __launch_bounds__(256) void prep_w_k(const float* __restrict__ W0,
                                                const float* __restrict__ W,
                                                unsigned short* __restrict__ fw) {
    const int gid = blockIdx.x * 256 + threadIdx.x;   // 0..8191
    const int l = gid & 63;
    const int s = (gid >> 6) & 3;
    const int n = (gid >> 8) & 7;
    const int m = gid >> 11;                          // 0..3
    const float* src = (m == 0) ? W0 : (W + (m - 1) * D * D);
    const int colw = n * 16 + (l & 15);
    const int k0 = s * 32 + ((l >> 4) << 3);
    unsigned short v[8];
#pragma unroll
    for (int j = 0; j < 8; ++j) v[j] = f2bf(src[(k0 + j) * D + colw]);
    uint4 o;
    o.x = v[0] | ((unsigned)v[1] << 16);
    o.y = v[2] | ((unsigned)v[3] << 16);
    o.z = v[4] | ((unsigned)v[5] << 16);
    o.w = v[6] | ((unsigned)v[7] << 16);
    reinterpret_cast<uint4*>(fw)[gid] = o;
}

// Y[100000x128] = X[100000x128] @ Wm[128x128], bf16 MFMA, f32 out (overwrite).
// One wave per 16-row tile; 8 n-tiles x 4 k-steps = 32 MFMAs.
__global__ __launch_bounds__(256) void gemm_k(const unsigned short* __restrict__ fx,
                                              const unsigned short* __restrict__ fwm,
                                              float* __restrict__ out) {
    const int wid = threadIdx.x >> 6;
    const int l = threadIdx.x & 63;
    const int t = blockIdx.x * 4 + wid;
    if (t >= NTILES) return;
    const bf16x8* ax = reinterpret_cast<const bf16x8*>(fx) + t * 256 + l;
    const bf16x8 a0 = ax[0];
    const bf16x8 a1 = ax[64];
    const bf16x8 a2 = ax[128];
    const bf16x8 a3 = ax[192];
    const bf16x8* bw = reinterpret_cast<const bf16x8*>(fwm) + l;
    f32x4 acc[8];
#pragma unroll
    for (int n = 0; n < 8; ++n) acc[n] = (f32x4){0.f, 0.f, 0.f, 0.f};
#pragma unroll
    for (int n = 0; n < 8; ++n) {
        acc[n] = __builtin_amdgcn_mfma_f32_16x16x32_bf16(a0, bw[(n * 4 + 0) * 64], acc[n], 0, 0, 0);
        acc[n] = __builtin_amdgcn_mfma_f32_16x16x32_bf16(a1, bw[(n * 4 + 1) * 64], acc[n], 0, 0, 0);
        acc[n] = __builtin_amdgcn_mfma_f32_16x16x32_bf16(a2, bw[(n * 4 + 2) * 64], acc[n], 0, 0, 0);
        acc[n] = __builtin_amdgcn_mfma_f32_16x16x32_bf16(a3, bw[(n * 4 + 3) * 64], acc[n], 0, 0, 0);
    }
    const int rbase = t * 16 + ((l >> 4) << 2);   // C/D: col = lane&15, row = (lane>>4)*4 + q
    const int colb = l & 15;
#pragma unroll
    for (int n = 0; n < 8; ++n) {
#pragma unroll
        for (int q = 0; q < 4; ++q)
            out[(rbase + q) * D + n * 16 + colb] = acc[n][q];
    }
}

// Undirected scatter: out[a] += Y[b], out[b] += Y[a]; one wave per edge, float2 per lane.
__global__ __launch_bounds__(256) void scatter_k(const float* __restrict__ Y,
                                                 const int* __restrict__ ea,
                                                 const int* __restrict__ eb,
                                                 float* __restrict__ out) {
    const int wid = threadIdx.x >> 6;
    const int l = threadIdx.x & 63;
    const int e = blockIdx.x * 4 + wid;
    if (e >= N_EDGES) return;
    const int a = ea[e];
    const int b = eb[e];
    const float2 va = reinterpret_cast<const float2*>(Y + (size_t)a * D)[l];
    const float2 vb = reinterpret_cast<const float2*>(Y + (size_t)b * D)[l];
    float* oa = out + (size_t)a * D + l * 2;
    float* ob = out + (size_t)b * D + l * 2;
    unsafeAtomicAdd(ob + 0, va.x);
    unsafeAtomicAdd(ob + 1, va.y);
    unsafeAtomicAdd(oa + 0, vb.x);
    unsafeAtomicAdd(oa + 1, vb.y);
}

// out = out * norms[node] + bias[unit]
__global__ __launch_bounds__(256) void finalize_k(float* __restrict__ out,
                                                  const float* __restrict__ norms,
                                                  const float* __restrict__ bias) {
    const int idx = blockIdx.x * 256 + threadIdx.x;   // one float4 each
    const int node = idx >> 5;                        // 32 float4 per node row
    const int c4 = idx & 31;
    f32x4 v = reinterpret_cast<f32x4*>(out)[idx];
    const float nm = norms[node];
    const f32x4 bb = reinterpret_cast<const f32x4*>(bias)[c4];
    v = v * nm + bb;
    reinterpret_cast<f32x4*>(out)[idx] = v;
}

extern "C" void kernel_launch(void* const* d_in, const int* in_sizes, int n_in,
                              void* d_out, int out_size, void* d_ws, size_t ws_size,
                              hipStream_t stream) {
    const float* X      = (const float*)d_in[0];
    const int*   ref_a  = (const int*)d_in[1];
    const int*   ref_b  = (const int*)d_in[2];
    const float* norms  = (const float*)d_in[3];
    const float* W0     = (const float*)d_in[4];
    const float* W      = (const float*)d_in[5];
    const float* bias   = (const float*)d_in[6];
    float* out = (float*)d_out;

    char* ws = (char*)d_ws;
    float* Y           = (float*)ws;                    // 51,200,000 B
    unsigned short* fx = (unsigned short*)(ws + 51200000);   // 25,600,000 B
    unsigned short* fw = (unsigned short*)(ws + 76800000);   // 131,072 B

    prep_x_k<<<NTILES, 256, 0, stream>>>(X, fx);
    prep_w_k<<<32, 256, 0, stream>>>(W0, W, fw);

    // acc = X @ W0   (overwrites the poisoned d_out)
    gemm_k<<<(NTILES + 3) / 4, 256, 0, stream>>>(fx, fw, out);

    for (int r = 0; r < 3; ++r) {
        // Y = X @ W[r]
        gemm_k<<<(NTILES + 3) / 4, 256, 0, stream>>>(fx, fw + (r + 1) * 16384, Y);
        // acc[a] += Y[b]; acc[b] += Y[a]
        scatter_k<<<N_EDGES / 4, 256, 0, stream>>>(Y, ref_a + (size_t)r * N_EDGES,
                                                   ref_b + (size_t)r * N_EDGES, out);
    }

    // out = acc * norms + bias
    finalize_k<<<(N_NODES * D / 4) / 256, 256, 0, stream>>>(out, norms, bias);
}

// Round 2
// 852.627 us; speedup vs baseline: 2.9522x; 2.9522x over previous
//
#include <hip/hip_runtime.h>
#include <stdint.h>

#define N_NODES 100000
#define N_EDGES 500000
#define D 128
#define NTILES 6250   // N_NODES / 16

typedef __bf16 bf16x8 __attribute__((ext_vector_type(8)));
typedef float f32x4 __attribute__((ext_vector_type(4)));

__device__ __forceinline__ unsigned short f2bf(float f) {
    union { float f; unsigned u; } v; v.f = f;
    unsigned u = v.u;
    u += 0x7fffu + ((u >> 16) & 1u);   // round-to-nearest-even
    return (unsigned short)(u >> 16);
}

__device__ __forceinline__ float bf2f(unsigned short h) {
    union { unsigned u; float f; } x; x.u = ((unsigned)h) << 16; return x.f;
}

// ---------------------------------------------------------------------------
// Weight prep: shuffle W0, W[0..2] into MFMA B-fragment order, bf16.
// Matrix m entry ((n*4 + s)*64 + l) holds Wm[s*32 + (l>>4)*8 + j][n*16 + (l&15)]
__global__ __launch_bounds__(256) void prep_w_k(const float* __restrict__ W0,
                                                const float* __restrict__ W,
                                                unsigned short* __restrict__ fw) {
    const int gid = blockIdx.x * 256 + threadIdx.x;   // 0..8191
    const int l = gid & 63;
    const int s = (gid >> 6) & 3;
    const int n = (gid >> 8) & 7;
    const int m = gid >> 11;                          // 0..3
    const float* src = (m == 0) ? W0 : (W + (m - 1) * D * D);
    const int colw = n * 16 + (l & 15);
    const int k0 = s * 32 + ((l >> 4) << 3);
    unsigned short v[8];
#pragma unroll
    for (int j = 0; j < 8; ++j) v[j] = f2bf(src[(k0 + j) * D + colw]);
    uint4 o;
    o.x = v[0] | ((unsigned)v[1] << 16);
    o.y = v[2] | ((unsigned)v[3] << 16);
    o.z = v[4] | ((unsigned)v[5] << 16);
    o.w = v[6] | ((unsigned)v[7] << 16);
    reinterpret_cast<uint4*>(fw)[gid] = o;
}

// ---------------------------------------------------------------------------
// CSR build. Directed edges per relation: (a->b gives dst=a,src=b) and (dst=b,src=a).
__global__ __launch_bounds__(256) void count_k(const int* __restrict__ ea,
                                               const int* __restrict__ eb,
                                               int* __restrict__ counts) {
    const int r = blockIdx.y;
    const int e = blockIdx.x * 256 + threadIdx.x;
    if (e >= N_EDGES) return;
    const int a = ea[(size_t)r * N_EDGES + e];
    const int b = eb[(size_t)r * N_EDGES + e];
    atomicAdd(&counts[r * N_NODES + a], 1);
    atomicAdd(&counts[r * N_NODES + b], 1);
}

// Exclusive scan of counts -> offsets, one block per relation, 2048 elems/iter.
__global__ __launch_bounds__(256) void scan_k(const int* __restrict__ counts,
                                              int* __restrict__ offs) {
    const int r = blockIdx.x;
    const int* c = counts + r * N_NODES;
    int* o = offs + r * (N_NODES + 1);
    __shared__ int sums[256];
    __shared__ int carry;
    if (threadIdx.x == 0) carry = 0;
    __syncthreads();
    for (int base = 0; base < N_NODES; base += 2048) {
        const int i0 = base + threadIdx.x * 8;
        int v[8];
        int s = 0;
#pragma unroll
        for (int j = 0; j < 8; ++j) {
            const int idx = i0 + j;
            v[j] = (idx < N_NODES) ? c[idx] : 0;
            s += v[j];
        }
        sums[threadIdx.x] = s;
        __syncthreads();
        for (int off = 1; off < 256; off <<= 1) {
            const int t = (threadIdx.x >= off) ? sums[threadIdx.x - off] : 0;
            __syncthreads();
            sums[threadIdx.x] += t;
            __syncthreads();
        }
        int excl = carry + sums[threadIdx.x] - s;
#pragma unroll
        for (int j = 0; j < 8; ++j) {
            const int idx = i0 + j;
            if (idx < N_NODES) o[idx] = excl;
            excl += v[j];
        }
        __syncthreads();
        if (threadIdx.x == 255) carry += sums[255];
        __syncthreads();
    }
    if (threadIdx.x == 0) o[N_NODES] = carry;
}

__global__ __launch_bounds__(256) void fill_k(const int* __restrict__ ea,
                                              const int* __restrict__ eb,
                                              const int* __restrict__ offs,
                                              int* __restrict__ cursor,
                                              int* __restrict__ eidx) {
    const int r = blockIdx.y;
    const int e = blockIdx.x * 256 + threadIdx.x;
    if (e >= N_EDGES) return;
    const int a = ea[(size_t)r * N_EDGES + e];
    const int b = eb[(size_t)r * N_EDGES + e];
    const int* o = offs + r * (N_NODES + 1);
    int* cur = cursor + r * N_NODES;
    int* ei = eidx + (size_t)r * (2 * N_EDGES);
    const int pa = o[a] + atomicAdd(&cur[a], 1);
    ei[pa] = b;
    const int pb = o[b] + atomicAdd(&cur[b], 1);
    ei[pb] = a;
}

// ---------------------------------------------------------------------------
// GEMM: [100000x128] @ Wm[128x128]. Reads X f32 directly (inline bf16 convert).
// One wave per 16-row tile; 8 n-tiles x 4 k-steps = 32 MFMAs.
// Output: f32 to outf (bf16out=0) or bf16 to outb (bf16out=1).
__global__ __launch_bounds__(256) void gemm_k(const float* __restrict__ X,
                                              const unsigned short* __restrict__ fwm,
                                              float* __restrict__ outf,
                                              unsigned short* __restrict__ outb,
                                              int bf16out) {
    const int wid = threadIdx.x >> 6;
    const int l = threadIdx.x & 63;
    const int t = blockIdx.x * 4 + wid;
    if (t >= NTILES) return;
    const float4* xr = reinterpret_cast<const float4*>(
        X + (size_t)(t * 16 + (l & 15)) * D + ((l >> 4) << 3));
    bf16x8 a[4];
#pragma unroll
    for (int s = 0; s < 4; ++s) {
        const float4 f0 = xr[s * 8];
        const float4 f1 = xr[s * 8 + 1];
        union { uint4 u; bf16x8 h; } pk;
        pk.u.x = f2bf(f0.x) | ((unsigned)f2bf(f0.y) << 16);
        pk.u.y = f2bf(f0.z) | ((unsigned)f2bf(f0.w) << 16);
        pk.u.z = f2bf(f1.x) | ((unsigned)f2bf(f1.y) << 16);
        pk.u.w = f2bf(f1.z) | ((unsigned)f2bf(f1.w) << 16);
        a[s] = pk.h;
    }
    const bf16x8* bw = reinterpret_cast<const bf16x8*>(fwm) + l;
    f32x4 acc[8];
#pragma unroll
    for (int n = 0; n < 8; ++n) acc[n] = (f32x4){0.f, 0.f, 0.f, 0.f};
#pragma unroll
    for (int n = 0; n < 8; ++n) {
#pragma unroll
        for (int s = 0; s < 4; ++s)
            acc[n] = __builtin_amdgcn_mfma_f32_16x16x32_bf16(a[s], bw[(n * 4 + s) * 64], acc[n], 0, 0, 0);
    }
    const int rbase = t * 16 + ((l >> 4) << 2);   // C/D: col = lane&15, row = (lane>>4)*4 + q
    const int colb = l & 15;
    if (bf16out) {
#pragma unroll
        for (int n = 0; n < 8; ++n)
#pragma unroll
            for (int q = 0; q < 4; ++q)
                outb[(size_t)(rbase + q) * D + n * 16 + colb] = f2bf(acc[n][q]);
    } else {
#pragma unroll
        for (int n = 0; n < 8; ++n)
#pragma unroll
            for (int q = 0; q < 4; ++q)
                outf[(size_t)(rbase + q) * D + n * 16 + colb] = acc[n][q];
    }
}

// ---------------------------------------------------------------------------
// Pull gather: one wave per destination node. out[n] += sum_{src in CSR[n]} Yb[src].
// Last relation fuses the finalize: out = (out+acc)*norms[n] + bias.
__global__ __launch_bounds__(256) void gather_k(const unsigned short* __restrict__ Yb,
                                                const int* __restrict__ offs,
                                                const int* __restrict__ eidx,
                                                float* __restrict__ out,
                                                const float* __restrict__ norms,
                                                const float* __restrict__ bias,
                                                int finalize) {
    const int wid = threadIdx.x >> 6;
    const int l = threadIdx.x & 63;
    const int n = blockIdx.x * 4 + wid;
    if (n >= N_NODES) return;
    const int s0 = offs[n];
    const int s1 = offs[n + 1];
    float ax = 0.f, ay = 0.f;
    for (int i = s0; i < s1; ++i) {
        const int src = eidx[i];
        const unsigned v = *reinterpret_cast<const unsigned*>(Yb + (size_t)src * D + l * 2);
        ax += bf2f((unsigned short)(v & 0xffff));
        ay += bf2f((unsigned short)(v >> 16));
    }
    float* op = out + (size_t)n * D + l * 2;
    float2 cur = *reinterpret_cast<float2*>(op);
    float rx = cur.x + ax;
    float ry = cur.y + ay;
    if (finalize) {
        const float nm = norms[n];
        const float2 bb = *reinterpret_cast<const float2*>(bias + l * 2);
        rx = rx * nm + bb.x;
        ry = ry * nm + bb.y;
    }
    float2 res = {rx, ry};
    *reinterpret_cast<float2*>(op) = res;
}

// ---------------------------------------------------------------------------
extern "C" void kernel_launch(void* const* d_in, const int* in_sizes, int n_in,
                              void* d_out, int out_size, void* d_ws, size_t ws_size,
                              hipStream_t stream) {
    const float* X      = (const float*)d_in[0];
    const int*   ref_a  = (const int*)d_in[1];
    const int*   ref_b  = (const int*)d_in[2];
    const float* norms  = (const float*)d_in[3];
    const float* W0     = (const float*)d_in[4];
    const float* W      = (const float*)d_in[5];
    const float* bias   = (const float*)d_in[6];
    float* out = (float*)d_out;

    char* ws = (char*)d_ws;
    unsigned short* Yb = (unsigned short*)ws;                 // 25,600,000 B
    unsigned short* fw = (unsigned short*)(ws + 25600000);    //    131,072 B
    int* counts = (int*)(ws + 25731072);                      //  1,200,000 B
    int* cursor = (int*)(ws + 26931072);                      //  1,200,000 B
    int* offs   = (int*)(ws + 28131072);                      //  1,200,016 B
    int* eidx   = (int*)(ws + 29331088);                      // 12,000,000 B
    // total ~41.3 MB

    // zero counts + cursor (contiguous)
    hipMemsetAsync(ws + 25731072, 0, 2400000, stream);

    prep_w_k<<<32, 256, 0, stream>>>(W0, W, fw);

    // CSR build for all 3 relations
    dim3 egrid((N_EDGES + 255) / 256, 3);
    count_k<<<egrid, 256, 0, stream>>>(ref_a, ref_b, counts);
    scan_k<<<3, 256, 0, stream>>>(counts, offs);
    fill_k<<<egrid, 256, 0, stream>>>(ref_a, ref_b, offs, cursor, eidx);

    // out = X @ W0 (f32, overwrites poisoned d_out)
    gemm_k<<<(NTILES + 3) / 4, 256, 0, stream>>>(X, fw, out, nullptr, 0);

    for (int r = 0; r < 3; ++r) {
        // Yb = bf16(X @ W[r])
        gemm_k<<<(NTILES + 3) / 4, 256, 0, stream>>>(X, fw + (r + 1) * 16384, nullptr, Yb, 1);
        // out[n] += sum Yb[neighbors]; last relation also applies *norms + bias
        gather_k<<<(N_NODES + 3) / 4, 256, 0, stream>>>(
            Yb, offs + r * (N_NODES + 1), eidx + (size_t)r * (2 * N_EDGES),
            out, norms, bias, (r == 2) ? 1 : 0);
    }
}

// Round 3
// 750.352 us; speedup vs baseline: 3.3546x; 1.1363x over previous
//
#include <hip/hip_runtime.h>
#include <stdint.h>

#define N_NODES 100000
#define N_EDGES 500000
#define D 128
#define NTILES 6250   // N_NODES / 16
#define NPART 8       // one partition per XCD
#define PART_SZ 12500 // N_NODES / NPART (exact)
#define CHUNKS 32     // edge-list chunks per partition group
#define CH_EDGES 15625 // N_EDGES / CHUNKS (exact)

typedef __bf16 bf16x8 __attribute__((ext_vector_type(8)));
typedef float f32x4 __attribute__((ext_vector_type(4)));

__device__ __forceinline__ unsigned short f2bf(float f) {
    union { float f; unsigned u; } v; v.f = f;
    unsigned u = v.u;
    u += 0x7fffu + ((u >> 16) & 1u);   // round-to-nearest-even
    return (unsigned short)(u >> 16);
}

__device__ __forceinline__ float bf2f(unsigned short h) {
    union { unsigned u; float f; } x; x.u = ((unsigned)h) << 16; return x.f;
}

// ---------------------------------------------------------------------------
// Weight prep: shuffle W0, W[0..2] into MFMA B-fragment order, bf16.
// Matrix m entry ((n*4 + s)*64 + l) holds Wm[s*32 + (l>>4)*8 + j][n*16 + (l&15)]
__global__ __launch_bounds__(256) void prep_w_k(const float* __restrict__ W0,
                                                const float* __restrict__ W,
                                                unsigned short* __restrict__ fw) {
    const int gid = blockIdx.x * 256 + threadIdx.x;   // 0..8191
    const int l = gid & 63;
    const int s = (gid >> 6) & 3;
    const int n = (gid >> 8) & 7;
    const int m = gid >> 11;                          // 0..3
    const float* src = (m == 0) ? W0 : (W + (m - 1) * D * D);
    const int colw = n * 16 + (l & 15);
    const int k0 = s * 32 + ((l >> 4) << 3);
    unsigned short v[8];
#pragma unroll
    for (int j = 0; j < 8; ++j) v[j] = f2bf(src[(k0 + j) * D + colw]);
    uint4 o;
    o.x = v[0] | ((unsigned)v[1] << 16);
    o.y = v[2] | ((unsigned)v[3] << 16);
    o.z = v[4] | ((unsigned)v[5] << 16);
    o.w = v[6] | ((unsigned)v[7] << 16);
    reinterpret_cast<uint4*>(fw)[gid] = o;
}

// ---------------------------------------------------------------------------
// XCD-partitioned CSR build. Block handles only dst nodes in its partition
// (p = blockIdx.x % 8 -> XCD p via round-robin dispatch) so counter/eidx
// cache lines stay in one XCD's L2 and collect all writes before writeback.
__global__ __launch_bounds__(256) void count_k(const int* __restrict__ ea,
                                               const int* __restrict__ eb,
                                               int* __restrict__ counts) {
    const int r = blockIdx.y;
    const int p = blockIdx.x & (NPART - 1);
    const int chunk = blockIdx.x >> 3;
    const int lo = p * PART_SZ;
    const int e0 = chunk * CH_EDGES;
    const int e1 = e0 + CH_EDGES;
    const int* pa = ea + (size_t)r * N_EDGES;
    const int* pb = eb + (size_t)r * N_EDGES;
    int* cnt = counts + r * N_NODES;
    for (int e = e0 + threadIdx.x; e < e1; e += 256) {
        const int a = pa[e];
        const int b = pb[e];
        if ((unsigned)(a - lo) < (unsigned)PART_SZ) atomicAdd(&cnt[a], 1);
        if ((unsigned)(b - lo) < (unsigned)PART_SZ) atomicAdd(&cnt[b], 1);
    }
}

// Exclusive scan of counts -> offsets, one block per relation.
__global__ __launch_bounds__(256) void scan_k(const int* __restrict__ counts,
                                              int* __restrict__ offs) {
    const int r = blockIdx.x;
    const int* c = counts + r * N_NODES;
    int* o = offs + r * (N_NODES + 1);
    __shared__ int sums[256];
    __shared__ int carry;
    if (threadIdx.x == 0) carry = 0;
    __syncthreads();
    for (int base = 0; base < N_NODES; base += 2048) {
        const int i0 = base + threadIdx.x * 8;
        int v[8];
        int s = 0;
#pragma unroll
        for (int j = 0; j < 8; ++j) {
            const int idx = i0 + j;
            v[j] = (idx < N_NODES) ? c[idx] : 0;
            s += v[j];
        }
        sums[threadIdx.x] = s;
        __syncthreads();
        for (int off = 1; off < 256; off <<= 1) {
            const int t = (threadIdx.x >= off) ? sums[threadIdx.x - off] : 0;
            __syncthreads();
            sums[threadIdx.x] += t;
            __syncthreads();
        }
        int excl = carry + sums[threadIdx.x] - s;
#pragma unroll
        for (int j = 0; j < 8; ++j) {
            const int idx = i0 + j;
            if (idx < N_NODES) o[idx] = excl;
            excl += v[j];
        }
        __syncthreads();
        if (threadIdx.x == 255) carry += sums[255];
        __syncthreads();
    }
    if (threadIdx.x == 0) o[N_NODES] = carry;
}

__global__ __launch_bounds__(256) void fill_k(const int* __restrict__ ea,
                                              const int* __restrict__ eb,
                                              const int* __restrict__ offs,
                                              int* __restrict__ cursor,
                                              int* __restrict__ eidx) {
    const int r = blockIdx.y;
    const int p = blockIdx.x & (NPART - 1);
    const int chunk = blockIdx.x >> 3;
    const int lo = p * PART_SZ;
    const int e0 = chunk * CH_EDGES;
    const int e1 = e0 + CH_EDGES;
    const int* pa = ea + (size_t)r * N_EDGES;
    const int* pb = eb + (size_t)r * N_EDGES;
    const int* o = offs + r * (N_NODES + 1);
    int* cur = cursor + r * N_NODES;
    int* ei = eidx + (size_t)r * (2 * N_EDGES);
    for (int e = e0 + threadIdx.x; e < e1; e += 256) {
        const int a = pa[e];
        const int b = pb[e];
        if ((unsigned)(a - lo) < (unsigned)PART_SZ) {
            const int pos = o[a] + atomicAdd(&cur[a], 1);
            ei[pos] = b;
        }
        if ((unsigned)(b - lo) < (unsigned)PART_SZ) {
            const int pos = o[b] + atomicAdd(&cur[b], 1);
            ei[pos] = a;
        }
    }
}

// ---------------------------------------------------------------------------
// Fused 4-matrix GEMM: reads X once, writes out = X@W0 (f32) and
// Yb[r] = bf16(X@W[r]) for r=0..2. One wave per 16-row tile.
__global__ __launch_bounds__(256) void gemm4_k(const float* __restrict__ X,
                                               const unsigned short* __restrict__ fw,
                                               float* __restrict__ out,
                                               unsigned short* __restrict__ Yb) {
    const int wid = threadIdx.x >> 6;
    const int l = threadIdx.x & 63;
    const int t = blockIdx.x * 4 + wid;
    if (t >= NTILES) return;
    const float4* xr = reinterpret_cast<const float4*>(
        X + (size_t)(t * 16 + (l & 15)) * D + ((l >> 4) << 3));
    bf16x8 a[4];
#pragma unroll
    for (int s = 0; s < 4; ++s) {
        const float4 f0 = xr[s * 8];
        const float4 f1 = xr[s * 8 + 1];
        union { uint4 u; bf16x8 h; } pk;
        pk.u.x = f2bf(f0.x) | ((unsigned)f2bf(f0.y) << 16);
        pk.u.y = f2bf(f0.z) | ((unsigned)f2bf(f0.w) << 16);
        pk.u.z = f2bf(f1.x) | ((unsigned)f2bf(f1.y) << 16);
        pk.u.w = f2bf(f1.z) | ((unsigned)f2bf(f1.w) << 16);
        a[s] = pk.h;
    }
    const bf16x8* bw = reinterpret_cast<const bf16x8*>(fw) + l;
    const int rbase = t * 16 + ((l >> 4) << 2);   // C/D: col = lane&15, row = (lane>>4)*4 + q
    const int colb = l & 15;
#pragma unroll
    for (int m = 0; m < 4; ++m) {
        f32x4 acc[8];
#pragma unroll
        for (int n = 0; n < 8; ++n) acc[n] = (f32x4){0.f, 0.f, 0.f, 0.f};
#pragma unroll
        for (int n = 0; n < 8; ++n) {
#pragma unroll
            for (int s = 0; s < 4; ++s)
                acc[n] = __builtin_amdgcn_mfma_f32_16x16x32_bf16(
                    a[s], bw[m * 2048 + (n * 4 + s) * 64], acc[n], 0, 0, 0);
        }
        if (m == 0) {
#pragma unroll
            for (int n = 0; n < 8; ++n)
#pragma unroll
                for (int q = 0; q < 4; ++q)
                    out[(size_t)(rbase + q) * D + n * 16 + colb] = acc[n][q];
        } else {
            unsigned short* yo = Yb + (size_t)(m - 1) * N_NODES * D;
#pragma unroll
            for (int n = 0; n < 8; ++n)
#pragma unroll
                for (int q = 0; q < 4; ++q)
                    yo[(size_t)(rbase + q) * D + n * 16 + colb] = f2bf(acc[n][q]);
        }
    }
}

// Single-matrix GEMM (fallback path when ws is too small for 3 Y buffers).
__global__ __launch_bounds__(256) void gemm_k(const float* __restrict__ X,
                                              const unsigned short* __restrict__ fwm,
                                              float* __restrict__ outf,
                                              unsigned short* __restrict__ outb,
                                              int bf16out) {
    const int wid = threadIdx.x >> 6;
    const int l = threadIdx.x & 63;
    const int t = blockIdx.x * 4 + wid;
    if (t >= NTILES) return;
    const float4* xr = reinterpret_cast<const float4*>(
        X + (size_t)(t * 16 + (l & 15)) * D + ((l >> 4) << 3));
    bf16x8 a[4];
#pragma unroll
    for (int s = 0; s < 4; ++s) {
        const float4 f0 = xr[s * 8];
        const float4 f1 = xr[s * 8 + 1];
        union { uint4 u; bf16x8 h; } pk;
        pk.u.x = f2bf(f0.x) | ((unsigned)f2bf(f0.y) << 16);
        pk.u.y = f2bf(f0.z) | ((unsigned)f2bf(f0.w) << 16);
        pk.u.z = f2bf(f1.x) | ((unsigned)f2bf(f1.y) << 16);
        pk.u.w = f2bf(f1.z) | ((unsigned)f2bf(f1.w) << 16);
        a[s] = pk.h;
    }
    const bf16x8* bw = reinterpret_cast<const bf16x8*>(fwm) + l;
    f32x4 acc[8];
#pragma unroll
    for (int n = 0; n < 8; ++n) acc[n] = (f32x4){0.f, 0.f, 0.f, 0.f};
#pragma unroll
    for (int n = 0; n < 8; ++n) {
#pragma unroll
        for (int s = 0; s < 4; ++s)
            acc[n] = __builtin_amdgcn_mfma_f32_16x16x32_bf16(a[s], bw[(n * 4 + s) * 64], acc[n], 0, 0, 0);
    }
    const int rbase = t * 16 + ((l >> 4) << 2);
    const int colb = l & 15;
    if (bf16out) {
#pragma unroll
        for (int n = 0; n < 8; ++n)
#pragma unroll
            for (int q = 0; q < 4; ++q)
                outb[(size_t)(rbase + q) * D + n * 16 + colb] = f2bf(acc[n][q]);
    } else {
#pragma unroll
        for (int n = 0; n < 8; ++n)
#pragma unroll
            for (int q = 0; q < 4; ++q)
                outf[(size_t)(rbase + q) * D + n * 16 + colb] = acc[n][q];
    }
}

// ---------------------------------------------------------------------------
// Pull gather over nrel relations: one wave per destination node.
// out[n] += sum_r sum_{src in CSR_r[n]} Yb_r[src]; finalize applies *norms+bias.
__global__ __launch_bounds__(256) void gather_k(const unsigned short* __restrict__ Yb,
                                                const int* __restrict__ offs,
                                                const int* __restrict__ eidx,
                                                float* __restrict__ out,
                                                const float* __restrict__ norms,
                                                const float* __restrict__ bias,
                                                int nrel, int finalize) {
    const int wid = threadIdx.x >> 6;
    const int l = threadIdx.x & 63;
    const int n = blockIdx.x * 4 + wid;
    if (n >= N_NODES) return;
    float ax = 0.f, ay = 0.f;
    for (int r = 0; r < nrel; ++r) {
        const int* o = offs + r * (N_NODES + 1);
        const int* ei = eidx + (size_t)r * (2 * N_EDGES);
        const unsigned short* Y = Yb + (size_t)r * N_NODES * D;
        const int s1 = o[n + 1];
        for (int i = o[n]; i < s1; ++i) {
            const int src = ei[i];
            const unsigned v = *reinterpret_cast<const unsigned*>(Y + (size_t)src * D + l * 2);
            ax += bf2f((unsigned short)(v & 0xffff));
            ay += bf2f((unsigned short)(v >> 16));
        }
    }
    float* op = out + (size_t)n * D + l * 2;
    float2 cur = *reinterpret_cast<float2*>(op);
    float rx = cur.x + ax;
    float ry = cur.y + ay;
    if (finalize) {
        const float nm = norms[n];
        const float2 bb = *reinterpret_cast<const float2*>(bias + l * 2);
        rx = rx * nm + bb.x;
        ry = ry * nm + bb.y;
    }
    float2 res = {rx, ry};
    *reinterpret_cast<float2*>(op) = res;
}

// ---------------------------------------------------------------------------
extern "C" void kernel_launch(void* const* d_in, const int* in_sizes, int n_in,
                              void* d_out, int out_size, void* d_ws, size_t ws_size,
                              hipStream_t stream) {
    const float* X      = (const float*)d_in[0];
    const int*   ref_a  = (const int*)d_in[1];
    const int*   ref_b  = (const int*)d_in[2];
    const float* norms  = (const float*)d_in[3];
    const float* W0     = (const float*)d_in[4];
    const float* W      = (const float*)d_in[5];
    const float* bias   = (const float*)d_in[6];
    float* out = (float*)d_out;

    char* ws = (char*)d_ws;
    unsigned short* fw = (unsigned short*)ws;            //    131,072 B
    int* counts = (int*)(ws + 131072);                   //  1,200,000 B
    int* cursor = (int*)(ws + 1331072);                  //  1,200,000 B
    int* offs   = (int*)(ws + 2531072);                  //  1,200,016 B
    int* eidx   = (int*)(ws + 3731088);                  // 12,000,000 B
    unsigned short* Yb = (unsigned short*)(ws + 15731104); // 1 or 3 x 25,600,000 B

    const size_t need_fused = 15731104ULL + 3ULL * 25600000ULL;  // ~92.5 MB
    const int fused = (ws_size >= need_fused) ? 1 : 0;

    // zero counts + cursor (contiguous)
    hipMemsetAsync(ws + 131072, 0, 2400000, stream);

    prep_w_k<<<32, 256, 0, stream>>>(W0, W, fw);

    // XCD-partitioned CSR build, all 3 relations
    dim3 egrid(CHUNKS * NPART, 3);
    count_k<<<egrid, 256, 0, stream>>>(ref_a, ref_b, counts);
    scan_k<<<3, 256, 0, stream>>>(counts, offs);
    fill_k<<<egrid, 256, 0, stream>>>(ref_a, ref_b, offs, cursor, eidx);

    if (fused) {
        // out = X@W0 (f32), Yb[r] = bf16(X@W[r]) -- X read once
        gemm4_k<<<(NTILES + 3) / 4, 256, 0, stream>>>(X, fw, out, Yb);
        // single gather over all 3 relations + finalize
        gather_k<<<(N_NODES + 3) / 4, 256, 0, stream>>>(
            Yb, offs, eidx, out, norms, bias, 3, 1);
    } else {
        gemm_k<<<(NTILES + 3) / 4, 256, 0, stream>>>(X, fw, out, nullptr, 0);
        for (int r = 0; r < 3; ++r) {
            gemm_k<<<(NTILES + 3) / 4, 256, 0, stream>>>(X, fw + (r + 1) * 16384, nullptr, Yb, 1);
            gather_k<<<(N_NODES + 3) / 4, 256, 0, stream>>>(
                Yb, offs + r * (N_NODES + 1), eidx + (size_t)r * (2 * N_EDGES),
                out, norms, bias, 1, (r == 2) ? 1 : 0);
        }
    }
}

// Round 4
// 509.853 us; speedup vs baseline: 4.9370x; 1.4717x over previous
//
#include <hip/hip_runtime.h>
#include <stdint.h>

#define N_NODES 100000
#define N_EDGES 500000
#define D 128
#define NTILES 6250    // N_NODES / 16
#define NPART 8        // one partition per XCD
#define PART_SZ 12500  // N_NODES / NPART (exact)
#define CHUNKS 32      // edge-list chunks per partition group
#define CH_EDGES 15625 // N_EDGES / CHUNKS (exact)
#define SBLK 49        // scan blocks: ceil(100000 / 2048)

typedef __bf16 bf16x8 __attribute__((ext_vector_type(8)));
typedef float f32x4 __attribute__((ext_vector_type(4)));

__device__ __forceinline__ unsigned short f2bf(float f) {
    union { float f; unsigned u; } v; v.f = f;
    unsigned u = v.u;
    u += 0x7fffu + ((u >> 16) & 1u);   // round-to-nearest-even
    return (unsigned short)(u >> 16);
}

__device__ __forceinline__ float asf(unsigned u) {
    union { unsigned u; float f; } x; x.u = u; return x.f;
}

// ---------------------------------------------------------------------------
// Weight prep: shuffle W0, W[0..2] into MFMA B-fragment order, bf16.
// Matrix m entry ((n*4 + s)*64 + l) holds Wm[s*32 + (l>>4)*8 + j][n*16 + (l&15)]
__global__ __launch_bounds__(256) void prep_w_k(const float* __restrict__ W0,
                                                const float* __restrict__ W,
                                                unsigned short* __restrict__ fw) {
    const int gid = blockIdx.x * 256 + threadIdx.x;   // 0..8191
    const int l = gid & 63;
    const int s = (gid >> 6) & 3;
    const int n = (gid >> 8) & 7;
    const int m = gid >> 11;                          // 0..3
    const float* src = (m == 0) ? W0 : (W + (m - 1) * D * D);
    const int colw = n * 16 + (l & 15);
    const int k0 = s * 32 + ((l >> 4) << 3);
    unsigned short v[8];
#pragma unroll
    for (int j = 0; j < 8; ++j) v[j] = f2bf(src[(k0 + j) * D + colw]);
    uint4 o;
    o.x = v[0] | ((unsigned)v[1] << 16);
    o.y = v[2] | ((unsigned)v[3] << 16);
    o.z = v[4] | ((unsigned)v[5] << 16);
    o.w = v[6] | ((unsigned)v[7] << 16);
    reinterpret_cast<uint4*>(fw)[gid] = o;
}

// ---------------------------------------------------------------------------
// Combined-relation CSR build, XCD-partitioned (p = blockIdx.x & 7 -> XCD p).
// counts[n] = total undirected degree of n over all 3 relations.
__global__ __launch_bounds__(256) void count_k(const int* __restrict__ ea,
                                               const int* __restrict__ eb,
                                               int* __restrict__ counts) {
    const int r = blockIdx.y;
    const int p = blockIdx.x & (NPART - 1);
    const int chunk = blockIdx.x >> 3;
    const int lo = p * PART_SZ;
    const int e0 = chunk * CH_EDGES;
    const int e1 = e0 + CH_EDGES;
    const int* pa = ea + (size_t)r * N_EDGES;
    const int* pb = eb + (size_t)r * N_EDGES;
    for (int e = e0 + threadIdx.x; e < e1; e += 256) {
        const int a = pa[e];
        const int b = pb[e];
        if ((unsigned)(a - lo) < (unsigned)PART_SZ) atomicAdd(&counts[a], 1);
        if ((unsigned)(b - lo) < (unsigned)PART_SZ) atomicAdd(&counts[b], 1);
    }
}

// Phase 1: per-block exclusive scan (2048 elems/block) + block total.
__global__ __launch_bounds__(256) void scan1_k(const int* __restrict__ counts,
                                               int* __restrict__ offs,
                                               int* __restrict__ bsum) {
    __shared__ int sums[256];
    const int t = threadIdx.x;
    const int base = blockIdx.x * 2048 + t * 8;
    int v[8];
    int s = 0;
#pragma unroll
    for (int j = 0; j < 8; ++j) {
        const int idx = base + j;
        v[j] = (idx < N_NODES) ? counts[idx] : 0;
        s += v[j];
    }
    sums[t] = s;
    __syncthreads();
    for (int off = 1; off < 256; off <<= 1) {
        const int tv = (t >= off) ? sums[t - off] : 0;
        __syncthreads();
        sums[t] += tv;
        __syncthreads();
    }
    int excl = sums[t] - s;
#pragma unroll
    for (int j = 0; j < 8; ++j) {
        const int idx = base + j;
        if (idx < N_NODES) offs[idx] = excl;
        excl += v[j];
    }
    if (t == 255) bsum[blockIdx.x] = sums[255];
}

// Phase 2: scan the 49 block totals (single 64-thread block).
__global__ __launch_bounds__(64) void scan2_k(const int* __restrict__ bsum,
                                              int* __restrict__ bpre,
                                              int* __restrict__ offs) {
    __shared__ int s[64];
    const int t = threadIdx.x;
    const int v = (t < SBLK) ? bsum[t] : 0;
    s[t] = v;
    __syncthreads();
    for (int off = 1; off < 64; off <<= 1) {
        const int tv = (t >= off) ? s[t - off] : 0;
        __syncthreads();
        s[t] += tv;
        __syncthreads();
    }
    bpre[t] = s[t] - v;                    // exclusive block prefix
    if (t == 63) offs[N_NODES] = s[63];    // grand total (= 3,000,000)
}

// Phase 3: add block prefixes back.
__global__ __launch_bounds__(256) void scan3_k(int* __restrict__ offs,
                                               const int* __restrict__ bpre) {
    const int add = bpre[blockIdx.x];
    const int base = blockIdx.x * 2048 + threadIdx.x * 8;
#pragma unroll
    for (int j = 0; j < 8; ++j) {
        const int idx = base + j;
        if (idx < N_NODES) offs[idx] += add;
    }
}

// Fill combined CSR: src entries encode relation as src + r*N_NODES.
__global__ __launch_bounds__(256) void fill_k(const int* __restrict__ ea,
                                              const int* __restrict__ eb,
                                              const int* __restrict__ offs,
                                              int* __restrict__ cursor,
                                              int* __restrict__ eidx) {
    const int r = blockIdx.y;
    const int p = blockIdx.x & (NPART - 1);
    const int chunk = blockIdx.x >> 3;
    const int lo = p * PART_SZ;
    const int e0 = chunk * CH_EDGES;
    const int e1 = e0 + CH_EDGES;
    const int* pa = ea + (size_t)r * N_EDGES;
    const int* pb = eb + (size_t)r * N_EDGES;
    const int roff = r * N_NODES;
    for (int e = e0 + threadIdx.x; e < e1; e += 256) {
        const int a = pa[e];
        const int b = pb[e];
        if ((unsigned)(a - lo) < (unsigned)PART_SZ) {
            const int pos = offs[a] + atomicAdd(&cursor[a], 1);
            eidx[pos] = b + roff;
        }
        if ((unsigned)(b - lo) < (unsigned)PART_SZ) {
            const int pos = offs[b] + atomicAdd(&cursor[b], 1);
            eidx[pos] = a + roff;
        }
    }
}

// ---------------------------------------------------------------------------
// Fused 4-matrix GEMM: reads X once, writes out = X@W0 (f32) and
// Yb[r] = bf16(X@W[r]) for r=0..2 (contiguous 300000x128 bf16).
__global__ __launch_bounds__(256) void gemm4_k(const float* __restrict__ X,
                                               const unsigned short* __restrict__ fw,
                                               float* __restrict__ out,
                                               unsigned short* __restrict__ Yb) {
    const int wid = threadIdx.x >> 6;
    const int l = threadIdx.x & 63;
    const int t = blockIdx.x * 4 + wid;
    if (t >= NTILES) return;
    const float4* xr = reinterpret_cast<const float4*>(
        X + (size_t)(t * 16 + (l & 15)) * D + ((l >> 4) << 3));
    bf16x8 a[4];
#pragma unroll
    for (int s = 0; s < 4; ++s) {
        const float4 f0 = xr[s * 8];
        const float4 f1 = xr[s * 8 + 1];
        union { uint4 u; bf16x8 h; } pk;
        pk.u.x = f2bf(f0.x) | ((unsigned)f2bf(f0.y) << 16);
        pk.u.y = f2bf(f0.z) | ((unsigned)f2bf(f0.w) << 16);
        pk.u.z = f2bf(f1.x) | ((unsigned)f2bf(f1.y) << 16);
        pk.u.w = f2bf(f1.z) | ((unsigned)f2bf(f1.w) << 16);
        a[s] = pk.h;
    }
    const bf16x8* bw = reinterpret_cast<const bf16x8*>(fw) + l;
    const int rbase = t * 16 + ((l >> 4) << 2);   // C/D: col = lane&15, row = (lane>>4)*4 + q
    const int colb = l & 15;
#pragma unroll
    for (int m = 0; m < 4; ++m) {
        f32x4 acc[8];
#pragma unroll
        for (int n = 0; n < 8; ++n) acc[n] = (f32x4){0.f, 0.f, 0.f, 0.f};
#pragma unroll
        for (int n = 0; n < 8; ++n) {
#pragma unroll
            for (int s = 0; s < 4; ++s)
                acc[n] = __builtin_amdgcn_mfma_f32_16x16x32_bf16(
                    a[s], bw[m * 2048 + (n * 4 + s) * 64], acc[n], 0, 0, 0);
        }
        if (m == 0) {
#pragma unroll
            for (int n = 0; n < 8; ++n)
#pragma unroll
                for (int q = 0; q < 4; ++q)
                    out[(size_t)(rbase + q) * D + n * 16 + colb] = acc[n][q];
        } else {
            unsigned short* yo = Yb + (size_t)(m - 1) * N_NODES * D;
#pragma unroll
            for (int n = 0; n < 8; ++n)
#pragma unroll
                for (int q = 0; q < 4; ++q)
                    yo[(size_t)(rbase + q) * D + n * 16 + colb] = f2bf(acc[n][q]);
        }
    }
}

// ---------------------------------------------------------------------------
// Pull gather over the combined CSR: one wave per destination node.
// 4x unrolled neighbor loop for memory-level parallelism.
// out = (out + sum_{src} Yb[src]) * norms[n] + bias.
__global__ __launch_bounds__(256) void gather_k(const unsigned* __restrict__ Yu,
                                                const int* __restrict__ offs,
                                                const int* __restrict__ eidx,
                                                float* __restrict__ out,
                                                const float* __restrict__ norms,
                                                const float* __restrict__ bias) {
    const int wid = threadIdx.x >> 6;
    const int l = threadIdx.x & 63;
    const int n = blockIdx.x * 4 + wid;
    if (n >= N_NODES) return;
    const int s0 = offs[n];
    const int s1 = offs[n + 1];
    float ax = 0.f, ay = 0.f, bx = 0.f, by = 0.f;
    int i = s0;
    for (; i + 4 <= s1; i += 4) {
        const int c0 = eidx[i];
        const int c1 = eidx[i + 1];
        const int c2 = eidx[i + 2];
        const int c3 = eidx[i + 3];
        const unsigned v0 = Yu[(size_t)c0 * 64 + l];
        const unsigned v1 = Yu[(size_t)c1 * 64 + l];
        const unsigned v2 = Yu[(size_t)c2 * 64 + l];
        const unsigned v3 = Yu[(size_t)c3 * 64 + l];
        ax += asf(v0 << 16); ay += asf(v0 & 0xffff0000u);
        bx += asf(v1 << 16); by += asf(v1 & 0xffff0000u);
        ax += asf(v2 << 16); ay += asf(v2 & 0xffff0000u);
        bx += asf(v3 << 16); by += asf(v3 & 0xffff0000u);
    }
    for (; i < s1; ++i) {
        const unsigned v = Yu[(size_t)eidx[i] * 64 + l];
        ax += asf(v << 16); ay += asf(v & 0xffff0000u);
    }
    float* op = out + (size_t)n * D + l * 2;
    const float2 cur = *reinterpret_cast<const float2*>(op);
    const float nm = norms[n];
    const float2 bb = *reinterpret_cast<const float2*>(bias + l * 2);
    float2 res;
    res.x = (cur.x + ax + bx) * nm + bb.x;
    res.y = (cur.y + ay + by) * nm + bb.y;
    *reinterpret_cast<float2*>(op) = res;
}

// ---------------------------------------------------------------------------
extern "C" void kernel_launch(void* const* d_in, const int* in_sizes, int n_in,
                              void* d_out, int out_size, void* d_ws, size_t ws_size,
                              hipStream_t stream) {
    const float* X      = (const float*)d_in[0];
    const int*   ref_a  = (const int*)d_in[1];
    const int*   ref_b  = (const int*)d_in[2];
    const float* norms  = (const float*)d_in[3];
    const float* W0     = (const float*)d_in[4];
    const float* W      = (const float*)d_in[5];
    const float* bias   = (const float*)d_in[6];
    float* out = (float*)d_out;

    char* ws = (char*)d_ws;
    unsigned short* fw = (unsigned short*)ws;              //    131,072 B
    int* counts = (int*)(ws + 131072);                     //    400,000 B
    int* cursor = (int*)(ws + 531072);                     //    400,000 B
    int* bsum   = (int*)(ws + 931072);                     //        256 B
    int* bpre   = (int*)(ws + 931328);                     //        272 B
    int* offs   = (int*)(ws + 931600);                     //    400,016 B
    int* eidx   = (int*)(ws + 1331616);                    // 12,000,000 B
    unsigned short* Yb = (unsigned short*)(ws + 13331616); // 76,800,000 B
    // total ~90.1 MB (R3 confirmed ws >= 92.5 MB)

    // zero counts + cursor (contiguous)
    hipMemsetAsync(ws + 131072, 0, 800000, stream);

    prep_w_k<<<32, 256, 0, stream>>>(W0, W, fw);

    // combined-relation, XCD-partitioned CSR build
    dim3 egrid(CHUNKS * NPART, 3);
    count_k<<<egrid, 256, 0, stream>>>(ref_a, ref_b, counts);
    scan1_k<<<SBLK, 256, 0, stream>>>(counts, offs, bsum);
    scan2_k<<<1, 64, 0, stream>>>(bsum, bpre, offs);
    scan3_k<<<SBLK, 256, 0, stream>>>(offs, bpre);
    fill_k<<<egrid, 256, 0, stream>>>(ref_a, ref_b, offs, cursor, eidx);

    // out = X@W0 (f32), Yb[r] = bf16(X@W[r]) -- X read once
    gemm4_k<<<(NTILES + 3) / 4, 256, 0, stream>>>(X, fw, out, Yb);

    // single gather over combined CSR + fused finalize
    gather_k<<<(N_NODES + 3) / 4, 256, 0, stream>>>(
        (const unsigned*)Yb, offs, eidx, out, norms, bias);
}

// Round 5
// 492.489 us; speedup vs baseline: 5.1111x; 1.0353x over previous
//
#include <hip/hip_runtime.h>
#include <stdint.h>

#define N_NODES 100000
#define N_EDGES 500000
#define D 128
#define NTILES 6250    // N_NODES / 16
#define NPART 8        // one partition per XCD
#define PART_SZ 12500  // N_NODES / NPART (exact)
#define CHUNKS 32      // edge-list chunks per partition group
#define CH_EDGES 15625 // N_EDGES / CHUNKS (exact)
#define SBLK 49        // scan blocks: ceil(100000 / 2048)
#define PREP_BLKS 32   // prep_w blocks inside fused kernel 1
#define CNT_BLKS 1024  // count blocks inside fused kernel 1
#define GEMM_BLKS 1568 // ceil(6250/4)=1563 padded to a multiple of 8

typedef __bf16 bf16x8 __attribute__((ext_vector_type(8)));
typedef float f32x4 __attribute__((ext_vector_type(4)));

__device__ __forceinline__ unsigned short f2bf(float f) {
    union { float f; unsigned u; } v; v.f = f;
    unsigned u = v.u;
    u += 0x7fffu + ((u >> 16) & 1u);   // round-to-nearest-even
    return (unsigned short)(u >> 16);
}

__device__ __forceinline__ float asf(unsigned u) {
    union { unsigned u; float f; } x; x.u = u; return x.f;
}

// ---------------------------------------------------------------------------
// Fused kernel 1: blocks [0,32) shuffle weights into MFMA B-fragment order;
// blocks [32, 32+1024) do a single-pass unpartitioned degree count
// (atomics resolve at the shared coherence point; no partitioning needed).
__global__ __launch_bounds__(256) void prep_count_k(const float* __restrict__ W0,
                                                    const float* __restrict__ W,
                                                    unsigned short* __restrict__ fw,
                                                    const int* __restrict__ ea,
                                                    const int* __restrict__ eb,
                                                    int* __restrict__ counts) {
    const int bid = blockIdx.x;
    if (bid < PREP_BLKS) {
        const int gid = bid * 256 + threadIdx.x;          // 0..8191
        const int l = gid & 63;
        const int s = (gid >> 6) & 3;
        const int n = (gid >> 8) & 7;
        const int m = gid >> 11;                          // 0..3
        const float* src = (m == 0) ? W0 : (W + (m - 1) * D * D);
        const int colw = n * 16 + (l & 15);
        const int k0 = s * 32 + ((l >> 4) << 3);
        unsigned short v[8];
#pragma unroll
        for (int j = 0; j < 8; ++j) v[j] = f2bf(src[(k0 + j) * D + colw]);
        uint4 o;
        o.x = v[0] | ((unsigned)v[1] << 16);
        o.y = v[2] | ((unsigned)v[3] << 16);
        o.z = v[4] | ((unsigned)v[5] << 16);
        o.w = v[6] | ((unsigned)v[7] << 16);
        reinterpret_cast<uint4*>(fw)[gid] = o;
    } else {
        const int stride = CNT_BLKS * 256;
        for (int e = (bid - PREP_BLKS) * 256 + threadIdx.x; e < 3 * N_EDGES; e += stride) {
            atomicAdd(&counts[ea[e]], 1);
            atomicAdd(&counts[eb[e]], 1);
        }
    }
}

// ---------------------------------------------------------------------------
// Phase 1: per-block exclusive scan (2048 elems/block) + block total.
__global__ __launch_bounds__(256) void scan1_k(const int* __restrict__ counts,
                                               int* __restrict__ offs,
                                               int* __restrict__ bsum) {
    __shared__ int sums[256];
    const int t = threadIdx.x;
    const int base = blockIdx.x * 2048 + t * 8;
    int v[8];
    int s = 0;
#pragma unroll
    for (int j = 0; j < 8; ++j) {
        const int idx = base + j;
        v[j] = (idx < N_NODES) ? counts[idx] : 0;
        s += v[j];
    }
    sums[t] = s;
    __syncthreads();
    for (int off = 1; off < 256; off <<= 1) {
        const int tv = (t >= off) ? sums[t - off] : 0;
        __syncthreads();
        sums[t] += tv;
        __syncthreads();
    }
    int excl = sums[t] - s;
#pragma unroll
    for (int j = 0; j < 8; ++j) {
        const int idx = base + j;
        if (idx < N_NODES) offs[idx] = excl;
        excl += v[j];
    }
    if (t == 255) bsum[blockIdx.x] = sums[255];
}

// Phase 2: scan the 49 block totals (single 64-thread block).
__global__ __launch_bounds__(64) void scan2_k(const int* __restrict__ bsum,
                                              int* __restrict__ bpre,
                                              int* __restrict__ offs) {
    __shared__ int s[64];
    const int t = threadIdx.x;
    const int v = (t < SBLK) ? bsum[t] : 0;
    s[t] = v;
    __syncthreads();
    for (int off = 1; off < 64; off <<= 1) {
        const int tv = (t >= off) ? s[t - off] : 0;
        __syncthreads();
        s[t] += tv;
        __syncthreads();
    }
    bpre[t] = s[t] - v;                    // exclusive block prefix
    if (t == 63) offs[N_NODES] = s[63];    // grand total (= 3,000,000)
}

// Phase 3: add block prefixes back.
__global__ __launch_bounds__(256) void scan3_k(int* __restrict__ offs,
                                               const int* __restrict__ bpre) {
    const int add = bpre[blockIdx.x];
    const int base = blockIdx.x * 2048 + threadIdx.x * 8;
#pragma unroll
    for (int j = 0; j < 8; ++j) {
        const int idx = base + j;
        if (idx < N_NODES) offs[idx] += add;
    }
}

// ---------------------------------------------------------------------------
// Fused kernel 2: blocks [0, GEMM_BLKS) run the 4-matrix GEMM (reads X once,
// writes out = X@W0 f32 and Yb[r] = bf16(X@W[r]) r=0..2); blocks
// [GEMM_BLKS, +768) run the XCD-partitioned CSR fill (p = bid & 7 keeps each
// partition's eidx lines in one XCD's L2). The two roles are independent and
// overlap: GEMM is MFMA/BW-heavy, fill is atomic-latency-heavy.
__global__ __launch_bounds__(256) void gemm_fill_k(const float* __restrict__ X,
                                                   const unsigned short* __restrict__ fw,
                                                   float* __restrict__ out,
                                                   unsigned short* __restrict__ Yb,
                                                   const int* __restrict__ ea,
                                                   const int* __restrict__ eb,
                                                   const int* __restrict__ offs,
                                                   int* __restrict__ cursor,
                                                   int* __restrict__ eidx) {
    const int bid = blockIdx.x;
    if (bid < GEMM_BLKS) {
        const int wid = threadIdx.x >> 6;
        const int l = threadIdx.x & 63;
        const int t = bid * 4 + wid;
        if (t >= NTILES) return;
        const float4* xr = reinterpret_cast<const float4*>(
            X + (size_t)(t * 16 + (l & 15)) * D + ((l >> 4) << 3));
        bf16x8 a[4];
#pragma unroll
        for (int s = 0; s < 4; ++s) {
            const float4 f0 = xr[s * 8];
            const float4 f1 = xr[s * 8 + 1];
            union { uint4 u; bf16x8 h; } pk;
            pk.u.x = f2bf(f0.x) | ((unsigned)f2bf(f0.y) << 16);
            pk.u.y = f2bf(f0.z) | ((unsigned)f2bf(f0.w) << 16);
            pk.u.z = f2bf(f1.x) | ((unsigned)f2bf(f1.y) << 16);
            pk.u.w = f2bf(f1.z) | ((unsigned)f2bf(f1.w) << 16);
            a[s] = pk.h;
        }
        const bf16x8* bw = reinterpret_cast<const bf16x8*>(fw) + l;
        const int rbase = t * 16 + ((l >> 4) << 2);   // C/D: col=lane&15, row=(lane>>4)*4+q
        const int colb = l & 15;
#pragma unroll
        for (int m = 0; m < 4; ++m) {
            f32x4 acc[8];
#pragma unroll
            for (int n = 0; n < 8; ++n) acc[n] = (f32x4){0.f, 0.f, 0.f, 0.f};
#pragma unroll
            for (int n = 0; n < 8; ++n) {
#pragma unroll
                for (int s = 0; s < 4; ++s)
                    acc[n] = __builtin_amdgcn_mfma_f32_16x16x32_bf16(
                        a[s], bw[m * 2048 + (n * 4 + s) * 64], acc[n], 0, 0, 0);
            }
            if (m == 0) {
#pragma unroll
                for (int n = 0; n < 8; ++n)
#pragma unroll
                    for (int q = 0; q < 4; ++q)
                        out[(size_t)(rbase + q) * D + n * 16 + colb] = acc[n][q];
            } else {
                unsigned short* yo = Yb + (size_t)(m - 1) * N_NODES * D;
#pragma unroll
                for (int n = 0; n < 8; ++n)
#pragma unroll
                    for (int q = 0; q < 4; ++q)
                        yo[(size_t)(rbase + q) * D + n * 16 + colb] = f2bf(acc[n][q]);
            }
        }
    } else {
        const int k = bid - GEMM_BLKS;
        const int p = bid & (NPART - 1);   // == k & 7 since GEMM_BLKS % 8 == 0
        const int j = k >> 3;              // 0..95
        const int r = j >> 5;              // relation 0..2
        const int chunk = j & 31;
        const int lo = p * PART_SZ;
        const int e0 = chunk * CH_EDGES;
        const int e1 = e0 + CH_EDGES;
        const int* pa = ea + (size_t)r * N_EDGES;
        const int* pb = eb + (size_t)r * N_EDGES;
        const int roff = r * N_NODES;
        for (int e = e0 + threadIdx.x; e < e1; e += 256) {
            const int a = pa[e];
            const int b = pb[e];
            if ((unsigned)(a - lo) < (unsigned)PART_SZ) {
                const int pos = offs[a] + atomicAdd(&cursor[a], 1);
                eidx[pos] = b + roff;
            }
            if ((unsigned)(b - lo) < (unsigned)PART_SZ) {
                const int pos = offs[b] + atomicAdd(&cursor[b], 1);
                eidx[pos] = a + roff;
            }
        }
    }
}

// ---------------------------------------------------------------------------
// Pull gather over the combined CSR: one wave per destination node, 8x
// unrolled neighbor loop (8 outstanding 256B row loads per wave).
// out = (out + sum_{src} Yb[src]) * norms[n] + bias.
__global__ __launch_bounds__(256) void gather_k(const unsigned* __restrict__ Yu,
                                                const int* __restrict__ offs,
                                                const int* __restrict__ eidx,
                                                float* __restrict__ out,
                                                const float* __restrict__ norms,
                                                const float* __restrict__ bias) {
    const int wid = threadIdx.x >> 6;
    const int l = threadIdx.x & 63;
    const int n = blockIdx.x * 4 + wid;
    if (n >= N_NODES) return;
    const int s0 = offs[n];
    const int s1 = offs[n + 1];
    float ax = 0.f, ay = 0.f, bx = 0.f, by = 0.f;
    int i = s0;
    for (; i + 8 <= s1; i += 8) {
        int c[8];
        unsigned v[8];
#pragma unroll
        for (int j = 0; j < 8; ++j) c[j] = eidx[i + j];
#pragma unroll
        for (int j = 0; j < 8; ++j) v[j] = Yu[(size_t)c[j] * 64 + l];
#pragma unroll
        for (int j = 0; j < 8; j += 2) {
            ax += asf(v[j] << 16);     ay += asf(v[j] & 0xffff0000u);
            bx += asf(v[j + 1] << 16); by += asf(v[j + 1] & 0xffff0000u);
        }
    }
    for (; i + 4 <= s1; i += 4) {
        const int c0 = eidx[i], c1 = eidx[i + 1], c2 = eidx[i + 2], c3 = eidx[i + 3];
        const unsigned v0 = Yu[(size_t)c0 * 64 + l];
        const unsigned v1 = Yu[(size_t)c1 * 64 + l];
        const unsigned v2 = Yu[(size_t)c2 * 64 + l];
        const unsigned v3 = Yu[(size_t)c3 * 64 + l];
        ax += asf(v0 << 16); ay += asf(v0 & 0xffff0000u);
        bx += asf(v1 << 16); by += asf(v1 & 0xffff0000u);
        ax += asf(v2 << 16); ay += asf(v2 & 0xffff0000u);
        bx += asf(v3 << 16); by += asf(v3 & 0xffff0000u);
    }
    for (; i < s1; ++i) {
        const unsigned v = Yu[(size_t)eidx[i] * 64 + l];
        ax += asf(v << 16); ay += asf(v & 0xffff0000u);
    }
    float* op = out + (size_t)n * D + l * 2;
    const float2 cur = *reinterpret_cast<const float2*>(op);
    const float nm = norms[n];
    const float2 bb = *reinterpret_cast<const float2*>(bias + l * 2);
    float2 res;
    res.x = (cur.x + ax + bx) * nm + bb.x;
    res.y = (cur.y + ay + by) * nm + bb.y;
    *reinterpret_cast<float2*>(op) = res;
}

// ---------------------------------------------------------------------------
extern "C" void kernel_launch(void* const* d_in, const int* in_sizes, int n_in,
                              void* d_out, int out_size, void* d_ws, size_t ws_size,
                              hipStream_t stream) {
    const float* X      = (const float*)d_in[0];
    const int*   ref_a  = (const int*)d_in[1];
    const int*   ref_b  = (const int*)d_in[2];
    const float* norms  = (const float*)d_in[3];
    const float* W0     = (const float*)d_in[4];
    const float* W      = (const float*)d_in[5];
    const float* bias   = (const float*)d_in[6];
    float* out = (float*)d_out;

    char* ws = (char*)d_ws;
    unsigned short* fw = (unsigned short*)ws;              //    131,072 B
    int* counts = (int*)(ws + 131072);                     //    400,000 B
    int* cursor = (int*)(ws + 531072);                     //    400,000 B
    int* bsum   = (int*)(ws + 931072);                     //        256 B
    int* bpre   = (int*)(ws + 931328);                     //        272 B
    int* offs   = (int*)(ws + 931600);                     //    400,016 B
    int* eidx   = (int*)(ws + 1331616);                    // 12,000,000 B
    unsigned short* Yb = (unsigned short*)(ws + 13331616); // 76,800,000 B
    // total ~90.1 MB (R3 confirmed ws >= 92.5 MB)

    // zero counts + cursor (contiguous)
    hipMemsetAsync(ws + 131072, 0, 800000, stream);

    // weights prep || single-pass degree count
    prep_count_k<<<PREP_BLKS + CNT_BLKS, 256, 0, stream>>>(W0, W, fw, ref_a, ref_b, counts);

    // 3-phase parallel exclusive scan -> offs
    scan1_k<<<SBLK, 256, 0, stream>>>(counts, offs, bsum);
    scan2_k<<<1, 64, 0, stream>>>(bsum, bpre, offs);
    scan3_k<<<SBLK, 256, 0, stream>>>(offs, bpre);

    // 4-matrix GEMM || XCD-partitioned CSR fill
    gemm_fill_k<<<GEMM_BLKS + CHUNKS * NPART * 3, 256, 0, stream>>>(
        X, fw, out, Yb, ref_a, ref_b, offs, cursor, eidx);

    // single gather over combined CSR + fused finalize
    gather_k<<<(N_NODES + 3) / 4, 256, 0, stream>>>(
        (const unsigned*)Yb, offs, eidx, out, norms, bias);
}